// Round 1
// baseline (31719.687 us; speedup 1.0000x reference)
//
#include <hip/hip_runtime.h>

// RNN scan, MI355X. Round 1: correctness-first two-phase structure.
// Phase 1: Xp = X@W_xh + b_h via bf16 MFMA, written into d_out[0..T) (in-place scratch).
// Phase 2: persistent 64-WG flag-synced scan; W_hh column slices resident in LDS.

typedef short bf16x8 __attribute__((ext_vector_type(8)));
typedef float f32x4 __attribute__((ext_vector_type(4)));

#define T_STEPS 2048
#define BATCH 64
#define HDIM 512
#define EDIM 512
#define BH (BATCH * HDIM)       // 32768 floats per timestep
#define NWG 64                  // 32 col-groups x 2 batch-groups
#define FLAGS_PER_STEP 64
#define LSTRIDE 516             // LDS row stride (floats): 16B-aligned, bank-spread

__device__ __forceinline__ short f2bf(float x) {
  unsigned u = __float_as_uint(x);
  u = (u + 0x7FFFu + ((u >> 16) & 1u)) >> 16;   // round-to-nearest-even
  return (short)u;
}

// ---------------- Phase 1: Xp = X @ W_xh + b_h  (bf16 MFMA) ----------------
// Tiles: 64x64 per block, BK=32 (one mfma K). Grid 16384 = 2048 m-tiles x 8 n-tiles,
// XCD-swizzled so the 8 n-tiles sharing one A-tile run on the same XCD (L2 reuse).
__global__ __launch_bounds__(256) void xp_gemm(const float* __restrict__ X,
                                               const float* __restrict__ Wxh,
                                               const float* __restrict__ bh,
                                               float* __restrict__ out) {
  __shared__ short As[64][40];   // [m][k] bf16, pad 32->40 (16B-aligned rows)
  __shared__ short Bs[64][40];   // [n][k] bf16 (W transposed for B-frag reads)
  const int bid = blockIdx.x;
  const int xcd = bid & 7;
  const int s   = bid >> 3;
  const int mt  = (xcd << 8) + (s >> 3);   // 0..2047
  const int nt  = s & 7;                   // 0..7
  const int tid = threadIdx.x;
  const int lane = tid & 63;
  const int wv   = tid >> 6;
  const int mrow = (wv >> 1) * 32;  // wave quadrant within 64x64
  const int ncol = (wv & 1) * 32;

  f32x4 acc00 = {0.f,0.f,0.f,0.f};
  f32x4 acc01 = acc00, acc10 = acc00, acc11 = acc00;

  const int ar = tid >> 2, aq = tid & 3;          // A staging: 64 rows x 4 quads of 8
  const int bk = tid >> 3, bn = (tid & 7) * 8;    // B staging: 32 k x 8 n-chunks

  for (int kt = 0; kt < 16; ++kt) {
    const float* asrc = X + (size_t)(mt * 64 + ar) * EDIM + kt * 32 + aq * 8;
    f32x4 a0 = *(const f32x4*)asrc;
    f32x4 a1 = *(const f32x4*)(asrc + 4);
    const float* bsrc = Wxh + (size_t)(kt * 32 + bk) * HDIM + nt * 64 + bn;
    f32x4 w0 = *(const f32x4*)bsrc;
    f32x4 w1 = *(const f32x4*)(bsrc + 4);

    bf16x8 ap;
    ap[0] = f2bf(a0[0]); ap[1] = f2bf(a0[1]); ap[2] = f2bf(a0[2]); ap[3] = f2bf(a0[3]);
    ap[4] = f2bf(a1[0]); ap[5] = f2bf(a1[1]); ap[6] = f2bf(a1[2]); ap[7] = f2bf(a1[3]);
    *(bf16x8*)&As[ar][aq * 8] = ap;
    Bs[bn + 0][bk] = f2bf(w0[0]);
    Bs[bn + 1][bk] = f2bf(w0[1]);
    Bs[bn + 2][bk] = f2bf(w0[2]);
    Bs[bn + 3][bk] = f2bf(w0[3]);
    Bs[bn + 4][bk] = f2bf(w1[0]);
    Bs[bn + 5][bk] = f2bf(w1[1]);
    Bs[bn + 6][bk] = f2bf(w1[2]);
    Bs[bn + 7][bk] = f2bf(w1[3]);
    __syncthreads();

    const int fm = lane & 15, fq = (lane >> 4) * 8;  // A[m=lane&15][k=quad*8+j]
    bf16x8 fa0 = *(bf16x8*)&As[mrow + fm][fq];
    bf16x8 fa1 = *(bf16x8*)&As[mrow + 16 + fm][fq];
    bf16x8 fb0 = *(bf16x8*)&Bs[ncol + fm][fq];
    bf16x8 fb1 = *(bf16x8*)&Bs[ncol + 16 + fm][fq];
    acc00 = __builtin_amdgcn_mfma_f32_16x16x32_bf16(fa0, fb0, acc00, 0, 0, 0);
    acc01 = __builtin_amdgcn_mfma_f32_16x16x32_bf16(fa0, fb1, acc01, 0, 0, 0);
    acc10 = __builtin_amdgcn_mfma_f32_16x16x32_bf16(fa1, fb0, acc10, 0, 0, 0);
    acc11 = __builtin_amdgcn_mfma_f32_16x16x32_bf16(fa1, fb1, acc11, 0, 0, 0);
    __syncthreads();
  }

  // C/D layout: col = lane&15, row = (lane>>4)*4 + i  (m89-verified)
  const int c = lane & 15, r4 = (lane >> 4) * 4;
  #pragma unroll
  for (int i = 0; i < 4; ++i) {
    int gm0 = mt * 64 + mrow + r4 + i;
    int gm1 = gm0 + 16;
    int gn0 = nt * 64 + ncol + c;
    int gn1 = gn0 + 16;
    out[(size_t)gm0 * HDIM + gn0] = acc00[i] + bh[gn0];
    out[(size_t)gm0 * HDIM + gn1] = acc01[i] + bh[gn1];
    out[(size_t)gm1 * HDIM + gn0] = acc10[i] + bh[gn0];
    out[(size_t)gm1 * HDIM + gn1] = acc11[i] + bh[gn1];
  }
}

// ---------------- Phase 2: persistent flag-synced scan ----------------
// 64 WGs = 32 col-groups (16 cols each, W slice in LDS) x 2 batch-groups (32 batches).
// h_t lives in d_out[t] (overwrites Xp_t). Flags: one int per (t, wg) in d_ws.
// LDS ~100KB -> exactly 1 WG/CU, 64 WGs always co-resident (no deadlock).
__global__ __launch_bounds__(256) void rnn_scan(const float* __restrict__ Whh,
                                                float* __restrict__ out,
                                                int* __restrict__ flags) {
  __shared__ float Wl[16][LSTRIDE];   // Wl[j][k] = Whh[k][jb+j]  (transposed slice)
  __shared__ float hl[32][LSTRIDE];   // h_{t-1} rows for this batch group
  const int tid = threadIdx.x;
  const int bid = blockIdx.x;
  const int cg = bid & 31;
  const int bg = bid >> 5;
  const int jb = cg * 16;

  for (int idx = tid; idx < 16 * 512; idx += 256) {
    int k = idx >> 4, j = idx & 15;
    Wl[j][k] = Whh[(size_t)k * HDIM + jb + j];
  }
  for (int idx = tid; idx < 32 * LSTRIDE; idx += 256) ((float*)hl)[idx] = 0.f;

  const int j  = tid & 15;
  const int b0 = tid >> 4;            // [0,16): thread covers local rows b0, b0+16
  const int jg = jb + j;
  const int gb0 = bg * 32 + b0;
  const int gb1 = gb0 + 16;
  const f32x4* wrow = (const f32x4*)&Wl[j][0];
  const f32x4* h0p  = (const f32x4*)&hl[b0][0];
  const f32x4* h1p  = (const f32x4*)&hl[b0 + 16][0];
  __syncthreads();

  for (int t = 0; t < T_STEPS; ++t) {
    if (t > 0) {
      // wait for the 32 producers of this batch-group's h_{t-1}
      if (tid < 32) {
        const int slot = (t - 1) * FLAGS_PER_STEP + bg * 32 + tid;
        while (__hip_atomic_load(&flags[slot], __ATOMIC_RELAXED,
                                 __HIP_MEMORY_SCOPE_AGENT) == 0)
          __builtin_amdgcn_s_sleep(2);
      }
      __syncthreads();
      __threadfence();   // acquire: invalidate caches so h loads see remote writes
      const f32x4* src =
          (const f32x4*)(out + (size_t)(t - 1) * BH + (size_t)bg * 32 * HDIM);
      #pragma unroll
      for (int i = 0; i < 16; ++i) {
        const int f = i * 256 + tid;          // 4096 float4 = 32 rows x 512
        f32x4 v = src[f];
        *(f32x4*)&hl[f >> 7][(f & 127) << 2] = v;
      }
      __syncthreads();
    }

    const size_t o0 = (size_t)t * BH + (size_t)gb0 * HDIM + jg;
    const size_t o1 = (size_t)t * BH + (size_t)gb1 * HDIM + jg;
    const float xp0 = out[o0];   // Xp_t element owned by this thread
    const float xp1 = out[o1];

    f32x4 acc0 = {0.f,0.f,0.f,0.f}, acc1 = {0.f,0.f,0.f,0.f};
    #pragma unroll 8
    for (int k4 = 0; k4 < 128; ++k4) {    // 512-long dot, float4 -> v_pk_fma_f32
      f32x4 w = wrow[k4];
      acc0 += w * h0p[k4];
      acc1 += w * h1p[k4];
    }
    const float s0 = acc0[0] + acc0[1] + acc0[2] + acc0[3];
    const float s1 = acc1[0] + acc1[1] + acc1[2] + acc1[3];
    const float v0 = tanhf(xp0 + s0);
    const float v1 = tanhf(xp1 + s1);
    out[o0] = v0;
    out[o1] = v1;
    if (t == T_STEPS - 1) {   // h_last tail output
      out[(size_t)T_STEPS * BH + (size_t)gb0 * HDIM + jg] = v0;
      out[(size_t)T_STEPS * BH + (size_t)gb1 * HDIM + jg] = v1;
    }

    __threadfence();     // release: make h_t visible device-wide
    __syncthreads();     // all threads' stores+fences done before flag
    if (tid == 0)
      __hip_atomic_store(&flags[t * FLAGS_PER_STEP + bid], 1,
                         __ATOMIC_RELEASE, __HIP_MEMORY_SCOPE_AGENT);
  }
}

extern "C" void kernel_launch(void* const* d_in, const int* in_sizes, int n_in,
                              void* d_out, int out_size, void* d_ws, size_t ws_size,
                              hipStream_t stream) {
  const float* X   = (const float*)d_in[0];
  const float* Wxh = (const float*)d_in[1];
  const float* Whh = (const float*)d_in[2];
  const float* bh  = (const float*)d_in[3];
  float* out = (float*)d_out;
  int* flags = (int*)d_ws;

  // zero the per-step flag array (d_ws is poisoned 0xAA before every launch)
  hipMemsetAsync(d_ws, 0, (size_t)T_STEPS * FLAGS_PER_STEP * sizeof(int), stream);
  xp_gemm<<<dim3(16384), dim3(256), 0, stream>>>(X, Wxh, bh, out);
  rnn_scan<<<dim3(NWG), dim3(256), 0, stream>>>(Whh, out, flags);
}

// Round 2
// 12739.118 us; speedup vs baseline: 2.4899x; 2.4899x over previous
//
#include <hip/hip_runtime.h>

// RNN scan, MI355X. Round 2: MFMA scan with W_hh resident in VGPRs.
// Phase 1: Xp = X@W_xh + b_h via bf16 MFMA into d_out[0..T) (unchanged from R1).
// Phase 2: 16 persistent WGs (64 batch x 32 cols each). W_hh B-fragments live in
//   registers for all 2048 steps; h exchanged in bf16 via double-buffered slots
//   in d_ws; per-step all-gather via global_load_lds; flag-per-(t,WG) sync.

typedef short bf16x8 __attribute__((ext_vector_type(8)));
typedef float f32x4 __attribute__((ext_vector_type(4)));

#define T_STEPS 2048
#define BATCH 64
#define HDIM 512
#define EDIM 512
#define BH (BATCH * HDIM)       // 32768 floats per timestep
#define NWG2 16                 // phase-2 workgroups (32 cols each)
#define HA_STRIDE 520           // shorts per hA row: 512 + 8 pad (16B-mult, bank shift)
#define STG_STRIDE 36           // floats per stg row: 32 + 4 pad (16B-mult)

__device__ __forceinline__ short f2bf(float x) {
  unsigned u = __float_as_uint(x);
  u = (u + 0x7FFFu + ((u >> 16) & 1u)) >> 16;   // round-to-nearest-even
  return (short)u;
}

// ---------------- Phase 1: Xp = X @ W_xh + b_h  (bf16 MFMA) ----------------
__global__ __launch_bounds__(256) void xp_gemm(const float* __restrict__ X,
                                               const float* __restrict__ Wxh,
                                               const float* __restrict__ bh,
                                               float* __restrict__ out) {
  __shared__ short As[64][40];
  __shared__ short Bs[64][40];
  const int bid = blockIdx.x;
  const int xcd = bid & 7;
  const int s   = bid >> 3;
  const int mt  = (xcd << 8) + (s >> 3);
  const int nt  = s & 7;
  const int tid = threadIdx.x;
  const int lane = tid & 63;
  const int wv   = tid >> 6;
  const int mrow = (wv >> 1) * 32;
  const int ncol = (wv & 1) * 32;

  f32x4 acc00 = {0.f,0.f,0.f,0.f};
  f32x4 acc01 = acc00, acc10 = acc00, acc11 = acc00;

  const int ar = tid >> 2, aq = tid & 3;
  const int bk = tid >> 3, bn = (tid & 7) * 8;

  for (int kt = 0; kt < 16; ++kt) {
    const float* asrc = X + (size_t)(mt * 64 + ar) * EDIM + kt * 32 + aq * 8;
    f32x4 a0 = *(const f32x4*)asrc;
    f32x4 a1 = *(const f32x4*)(asrc + 4);
    const float* bsrc = Wxh + (size_t)(kt * 32 + bk) * HDIM + nt * 64 + bn;
    f32x4 w0 = *(const f32x4*)bsrc;
    f32x4 w1 = *(const f32x4*)(bsrc + 4);

    bf16x8 ap;
    ap[0] = f2bf(a0[0]); ap[1] = f2bf(a0[1]); ap[2] = f2bf(a0[2]); ap[3] = f2bf(a0[3]);
    ap[4] = f2bf(a1[0]); ap[5] = f2bf(a1[1]); ap[6] = f2bf(a1[2]); ap[7] = f2bf(a1[3]);
    *(bf16x8*)&As[ar][aq * 8] = ap;
    Bs[bn + 0][bk] = f2bf(w0[0]);
    Bs[bn + 1][bk] = f2bf(w0[1]);
    Bs[bn + 2][bk] = f2bf(w0[2]);
    Bs[bn + 3][bk] = f2bf(w0[3]);
    Bs[bn + 4][bk] = f2bf(w1[0]);
    Bs[bn + 5][bk] = f2bf(w1[1]);
    Bs[bn + 6][bk] = f2bf(w1[2]);
    Bs[bn + 7][bk] = f2bf(w1[3]);
    __syncthreads();

    const int fm = lane & 15, fq = (lane >> 4) * 8;
    bf16x8 fa0 = *(bf16x8*)&As[mrow + fm][fq];
    bf16x8 fa1 = *(bf16x8*)&As[mrow + 16 + fm][fq];
    bf16x8 fb0 = *(bf16x8*)&Bs[ncol + fm][fq];
    bf16x8 fb1 = *(bf16x8*)&Bs[ncol + 16 + fm][fq];
    acc00 = __builtin_amdgcn_mfma_f32_16x16x32_bf16(fa0, fb0, acc00, 0, 0, 0);
    acc01 = __builtin_amdgcn_mfma_f32_16x16x32_bf16(fa0, fb1, acc01, 0, 0, 0);
    acc10 = __builtin_amdgcn_mfma_f32_16x16x32_bf16(fa1, fb0, acc10, 0, 0, 0);
    acc11 = __builtin_amdgcn_mfma_f32_16x16x32_bf16(fa1, fb1, acc11, 0, 0, 0);
    __syncthreads();
  }

  const int c = lane & 15, r4 = (lane >> 4) * 4;
  #pragma unroll
  for (int i = 0; i < 4; ++i) {
    int gm0 = mt * 64 + mrow + r4 + i;
    int gm1 = gm0 + 16;
    int gn0 = nt * 64 + ncol + c;
    int gn1 = gn0 + 16;
    out[(size_t)gm0 * HDIM + gn0] = acc00[i] + bh[gn0];
    out[(size_t)gm0 * HDIM + gn1] = acc01[i] + bh[gn1];
    out[(size_t)gm1 * HDIM + gn0] = acc10[i] + bh[gn0];
    out[(size_t)gm1 * HDIM + gn1] = acc11[i] + bh[gn1];
  }
}

// ---------------- Phase 2: MFMA scan, W in registers ----------------
// WG g owns cols [32g, 32g+32) for all 64 batches.
// Wave w owns batch rows [16w, 16w+16), both 16-col n-tiles.
// B-frags (W_hh) in VGPRs: Bf[2][16] = 128 VGPRs, loaded once.
// h exchange: bf16 slots (double-buffered) in d_ws; gather via global_load_lds.
__global__ __launch_bounds__(256, 1) void rnn_scan2(const float* __restrict__ Whh,
                                                    float* __restrict__ out,
                                                    int* __restrict__ flags,
                                                    short* __restrict__ slot0,
                                                    short* __restrict__ slot1) {
  __shared__ short hA[64 * HA_STRIDE];          // h_{t-1} bf16, [batch][k]
  __shared__ float stg[64][STG_STRIDE];         // h_t fp32 transpose staging

  const int tid  = threadIdx.x;
  const int g    = blockIdx.x;
  const int n0   = g * 32;
  const int w    = tid >> 6;
  const int lane = tid & 63;
  const int ln   = lane & 15;        // col within n-tile / m within m-tile
  const int kq   = (lane >> 4) * 8;  // k-run start within 32-k block
  const int r0   = (lane >> 4) * 4;  // C-layout row base
  const int mbase = w * 16;

  // ---- one-time: load W_hh B-fragments into registers (bf16) ----
  bf16x8 Bf[2][16];
  #pragma unroll
  for (int nt = 0; nt < 2; ++nt) {
    #pragma unroll
    for (int ks = 0; ks < 16; ++ks) {
      const float* src = Whh + (size_t)(ks * 32 + kq) * HDIM + n0 + nt * 16 + ln;
      bf16x8 f;
      #pragma unroll
      for (int j = 0; j < 8; ++j) f[j] = f2bf(src[(size_t)j * HDIM]);
      Bf[nt][ks] = f;
    }
  }

  // zero hA (step 0 multiplies by h_0 = 0)
  for (int i = tid; i < 64 * HA_STRIDE; i += 256) hA[i] = 0;
  __syncthreads();

  const int b  = tid >> 2;            // readout row (0..63)
  const int c0 = (tid & 3) * 8;       // readout col chunk

  for (int t = 0; t < T_STEPS; ++t) {
    // ---- prefetch Xp_t (C-layout, own cols) before the poll ----
    const size_t xbase = (size_t)t * BH + (size_t)(mbase + r0) * HDIM + n0 + ln;
    f32x4 acc0, acc1;
    #pragma unroll
    for (int i = 0; i < 4; ++i) {
      acc0[i] = out[xbase + (size_t)i * HDIM];
      acc1[i] = out[xbase + (size_t)i * HDIM + 16];
    }

    if (t > 0) {
      if (tid < NWG2) {
        const int slot = (t - 1) * NWG2 + tid;
        while (__hip_atomic_load(&flags[slot], __ATOMIC_RELAXED,
                                 __HIP_MEMORY_SCOPE_AGENT) == 0)
          __builtin_amdgcn_s_sleep(2);
      }
      __syncthreads();
      __threadfence();   // acquire: invalidate L1/L2 before reading remote h
      const short* sprev = ((t - 1) & 1) ? slot1 : slot0;
      // gather full h_{t-1} (64 rows x 512 bf16) -> hA; 1 row = 1 wave-instr
      #pragma unroll
      for (int i = 0; i < 16; ++i) {
        const int r = mbase + i;     // wave w covers rows 16w..16w+15
        const short* gp = sprev + (size_t)r * HDIM + lane * 8;
        __builtin_amdgcn_global_load_lds(
            (const __attribute__((address_space(1))) void*)gp,
            (__attribute__((address_space(3))) void*)&hA[r * HA_STRIDE],
            16, 0, 0);
      }
    }
    __syncthreads();     // gather complete (barrier drains vmcnt)

    // ---- MFMA: h_{t-1} @ W_slice, C initialized with Xp ----
    const short* arow = &hA[(mbase + ln) * HA_STRIDE + kq];
    #pragma unroll
    for (int ks = 0; ks < 16; ++ks) {
      bf16x8 a = *(const bf16x8*)(arow + ks * 32);
      acc0 = __builtin_amdgcn_mfma_f32_16x16x32_bf16(a, Bf[0][ks], acc0, 0, 0, 0);
      acc1 = __builtin_amdgcn_mfma_f32_16x16x32_bf16(a, Bf[1][ks], acc1, 0, 0, 0);
    }

    // ---- tanh + stage to LDS (transpose to row-major) ----
    #pragma unroll
    for (int i = 0; i < 4; ++i) {
      stg[mbase + r0 + i][ln]      = tanhf(acc0[i]);
      stg[mbase + r0 + i][ln + 16] = tanhf(acc1[i]);
    }
    __syncthreads();

    // ---- coalesced writeout: fp32 -> out[t], bf16 -> slot[t&1] ----
    {
      f32x4 lo = *(const f32x4*)&stg[b][c0];
      f32x4 hi = *(const f32x4*)&stg[b][c0 + 4];
      float* op = out + (size_t)t * BH + (size_t)b * HDIM + n0 + c0;
      *(f32x4*)op = lo;
      *(f32x4*)(op + 4) = hi;
      short* scur = (((t & 1) ? slot1 : slot0) + (size_t)b * HDIM + n0 + c0);
      bf16x8 pk;
      pk[0] = f2bf(lo[0]); pk[1] = f2bf(lo[1]); pk[2] = f2bf(lo[2]); pk[3] = f2bf(lo[3]);
      pk[4] = f2bf(hi[0]); pk[5] = f2bf(hi[1]); pk[6] = f2bf(hi[2]); pk[7] = f2bf(hi[3]);
      *(bf16x8*)scur = pk;
      if (t == T_STEPS - 1) {   // h_last tail output
        float* lp = out + (size_t)T_STEPS * BH + (size_t)b * HDIM + n0 + c0;
        *(f32x4*)lp = lo;
        *(f32x4*)(lp + 4) = hi;
      }
    }

    __threadfence();     // release: drain stores, write back L2
    __syncthreads();
    if (tid == 0)
      __hip_atomic_store(&flags[t * NWG2 + g], 1,
                         __ATOMIC_RELEASE, __HIP_MEMORY_SCOPE_AGENT);
  }
}

extern "C" void kernel_launch(void* const* d_in, const int* in_sizes, int n_in,
                              void* d_out, int out_size, void* d_ws, size_t ws_size,
                              hipStream_t stream) {
  const float* X   = (const float*)d_in[0];
  const float* Wxh = (const float*)d_in[1];
  const float* Whh = (const float*)d_in[2];
  const float* bh  = (const float*)d_in[3];
  float* out = (float*)d_out;

  // ws layout: [0,128K) flags, [128K,192K) slot0, [192K,256K) slot1
  int*   flags = (int*)d_ws;
  short* slot0 = (short*)((char*)d_ws + (size_t)T_STEPS * NWG2 * sizeof(int));
  short* slot1 = slot0 + (size_t)BATCH * HDIM;

  hipMemsetAsync(d_ws, 0, (size_t)T_STEPS * NWG2 * sizeof(int), stream);
  xp_gemm<<<dim3(16384), dim3(256), 0, stream>>>(X, Wxh, bh, out);
  rnn_scan2<<<dim3(NWG2), dim3(256), 0, stream>>>(Whh, out, flags, slot0, slot1);
}